// Round 5
// baseline (558.713 us; speedup 1.0000x reference)
//
#include <hip/hip_runtime.h>
#include <math.h>

// Problem constants (match reference)
#define BB    16
#define NSRC  1024
#define NDST  4096
#define CIN   256
#define CSKIP 128
#define CHID  256
#define NROWS (BB * NDST)   // 65536 output rows

// ---------------------------------------------------------------------------
// Kernel 1: 3-NN per dst point within its cloud; emit global src indices and
// normalized inverse-squared-distance weights.
// Grid: BB * (NDST/256) = 256 blocks, 256 threads (1 dst point / thread).
// ---------------------------------------------------------------------------
__global__ __launch_bounds__(256) void knn_kernel(
    const float* __restrict__ pos,       // [BB*NSRC, 3]
    const float* __restrict__ pos_skip,  // [BB*NDST, 3]
    int*   __restrict__ nidx,            // [BB*NDST, 3] global src row ids
    float* __restrict__ nw)              // [BB*NDST, 3] normalized weights
{
    __shared__ float sx[NSRC], sy[NSRC], sz[NSRC];
    const int bpc = NDST / 256;                  // 16 blocks per cloud
    const int b   = blockIdx.x / bpc;
    const int r0  = (blockIdx.x % bpc) * 256;
    const int tid = threadIdx.x;

    const float* ps = pos + (size_t)b * NSRC * 3;
    for (int i = tid; i < NSRC; i += 256) {
        sx[i] = ps[i * 3 + 0];
        sy[i] = ps[i * 3 + 1];
        sz[i] = ps[i * 3 + 2];
    }
    __syncthreads();

    const int dr = b * NDST + r0 + tid;
    const float qx = pos_skip[dr * 3 + 0];
    const float qy = pos_skip[dr * 3 + 1];
    const float qz = pos_skip[dr * 3 + 2];

    float b0 = 3.4e38f, b1 = 3.4e38f, b2 = 3.4e38f;
    int   i0 = 0, i1 = 0, i2 = 0;
#pragma unroll 4
    for (int j = 0; j < NSRC; ++j) {
        const float dx = qx - sx[j];
        const float dy = qy - sy[j];
        const float dz = qz - sz[j];
        const float d  = dx * dx + dy * dy + dz * dz;
        if (d < b2) {                    // strict < keeps earlier index on ties (top_k order)
            if (d < b0)      { b2 = b1; i2 = i1; b1 = b0; i1 = i0; b0 = d; i0 = j; }
            else if (d < b1) { b2 = b1; i2 = i1; b1 = d;  i1 = j; }
            else             { b2 = d;  i2 = j; }
        }
    }
    const float w0 = 1.0f / (b0 + 1e-16f);
    const float w1 = 1.0f / (b1 + 1e-16f);
    const float w2 = 1.0f / (b2 + 1e-16f);
    const float inv = 1.0f / (w0 + w1 + w2);

    nidx[dr * 3 + 0] = b * NSRC + i0;
    nidx[dr * 3 + 1] = b * NSRC + i1;
    nidx[dr * 3 + 2] = b * NSRC + i2;
    nw[dr * 3 + 0] = w0 * inv;
    nw[dr * 3 + 1] = w1 * inv;
    nw[dr * 3 + 2] = w2 * inv;
}

// ---------------------------------------------------------------------------
// Kernel 2/3: fp32 GEMM, BM=64, BN=256 (full N), BK=16, 256 threads.
// Thread tile 4 rows x 16 cols (cols tx*4 + j4*64). acc = 64 VGPRs.
// INTERP: A-tile is built on the fly: cols [0,256) = knn-weighted gather of x,
//         cols [256,384) = x_skip.  (each A row touched by exactly 1 block)
// ---------------------------------------------------------------------------
template <int KDIM, bool INTERP, bool RELU>
__global__ __launch_bounds__(256) void mlp_gemm_kernel(
    const float* __restrict__ Asrc,    // INTERP ? x [*,256] : h [*,KDIM]
    const float* __restrict__ x_skip,  // [*,128] (INTERP only)
    const int*   __restrict__ nidx,    // [*,3]   (INTERP only)
    const float* __restrict__ nw,      // [*,3]   (INTERP only)
    const float* __restrict__ W,       // [KDIM, 256] row-major
    const float* __restrict__ bias,    // [256]
    float*       __restrict__ out)     // [*,256]
{
    constexpr int BM = 64, BN = 256, BK = 16;
    __shared__ float As[BK][68];       // transposed A tile, stride 68 (16B-aligned, conflict-lite)
    __shared__ float Ws[BK][BN];       // W tile
    __shared__ int   sIdx[BM][3];
    __shared__ float sW[BM][3];

    const int tid     = threadIdx.x;
    const int rowBase = blockIdx.x * BM;

    if (INTERP) {
        if (tid < BM * 3) {
            const int r = tid / 3, j = tid % 3;
            sIdx[r][j] = nidx[(size_t)(rowBase + r) * 3 + j];
            sW[r][j]   = nw[(size_t)(rowBase + r) * 3 + j];
        }
        __syncthreads();
    }

    const int tx = tid & 15;    // col group
    const int ty = tid >> 4;    // row group (rows ty*4 .. ty*4+3)

    float acc[4][16];
#pragma unroll
    for (int i = 0; i < 4; ++i)
#pragma unroll
        for (int j = 0; j < 16; ++j) acc[i][j] = 0.0f;

    const int lr  = tid >> 2;   // A-load row 0..63
    const int lk4 = tid & 3;    // which float4 of the 16-wide k chunk

    for (int kt = 0; kt < KDIM; kt += BK) {
        // ---- load A tile (to regs) ----
        float4 av;
        if (INTERP) {
            if (kt < CIN) {
                const float4* x4 = (const float4*)Asrc;
                const int c4 = (kt >> 2) + lk4;           // 0..63
                const float w0 = sW[lr][0], w1 = sW[lr][1], w2 = sW[lr][2];
                const float4 f0 = x4[(size_t)sIdx[lr][0] * (CIN / 4) + c4];
                const float4 f1 = x4[(size_t)sIdx[lr][1] * (CIN / 4) + c4];
                const float4 f2 = x4[(size_t)sIdx[lr][2] * (CIN / 4) + c4];
                av.x = w0 * f0.x + w1 * f1.x + w2 * f2.x;
                av.y = w0 * f0.y + w1 * f1.y + w2 * f2.y;
                av.z = w0 * f0.z + w1 * f1.z + w2 * f2.z;
                av.w = w0 * f0.w + w1 * f1.w + w2 * f2.w;
            } else {
                const float4* xs4 = (const float4*)x_skip;
                av = xs4[(size_t)(rowBase + lr) * (CSKIP / 4) + ((kt - CIN) >> 2) + lk4];
            }
        } else {
            const float4* a4 = (const float4*)Asrc;
            av = a4[(size_t)(rowBase + lr) * (KDIM / 4) + (kt >> 2) + lk4];
        }
        // ---- load W tile (to regs) ----
        float4 wv[4];
#pragma unroll
        for (int i = 0; i < 4; ++i) {
            const int f  = tid + i * 256;   // 0..1023 float4s
            const int k  = f >> 6;
            const int c4 = f & 63;
            wv[i] = ((const float4*)(W + (size_t)kt * BN))[k * (BN / 4) + c4];
        }
        __syncthreads();   // previous tile's compute done before overwrite
        // ---- store to LDS ----
        As[lk4 * 4 + 0][lr] = av.x;
        As[lk4 * 4 + 1][lr] = av.y;
        As[lk4 * 4 + 2][lr] = av.z;
        As[lk4 * 4 + 3][lr] = av.w;
#pragma unroll
        for (int i = 0; i < 4; ++i) {
            const int f  = tid + i * 256;
            const int k  = f >> 6;
            const int c4 = f & 63;
            *(float4*)&Ws[k][c4 * 4] = wv[i];
        }
        __syncthreads();
        // ---- compute ----
#pragma unroll
        for (int k = 0; k < BK; ++k) {
            const float4 a   = *(const float4*)&As[k][ty * 4];
            const float4 w0v = *(const float4*)&Ws[k][tx * 4 + 0];
            const float4 w1v = *(const float4*)&Ws[k][tx * 4 + 64];
            const float4 w2v = *(const float4*)&Ws[k][tx * 4 + 128];
            const float4 w3v = *(const float4*)&Ws[k][tx * 4 + 192];
            const float aa[4]  = { a.x, a.y, a.z, a.w };
            const float bb[16] = { w0v.x, w0v.y, w0v.z, w0v.w,
                                   w1v.x, w1v.y, w1v.z, w1v.w,
                                   w2v.x, w2v.y, w2v.z, w2v.w,
                                   w3v.x, w3v.y, w3v.z, w3v.w };
#pragma unroll
            for (int i = 0; i < 4; ++i)
#pragma unroll
                for (int j = 0; j < 16; ++j)
                    acc[i][j] += aa[i] * bb[j];
        }
    }

    // ---- epilogue: bias (+ReLU), coalesced float4 stores ----
#pragma unroll
    for (int j4 = 0; j4 < 4; ++j4) {
        const int col = tx * 4 + j4 * 64;
        const float4 bv = *(const float4*)&bias[col];
#pragma unroll
        for (int i = 0; i < 4; ++i) {
            const int row = rowBase + ty * 4 + i;
            float4 o;
            o.x = acc[i][j4 * 4 + 0] + bv.x;
            o.y = acc[i][j4 * 4 + 1] + bv.y;
            o.z = acc[i][j4 * 4 + 2] + bv.z;
            o.w = acc[i][j4 * 4 + 3] + bv.w;
            if (RELU) {
                o.x = fmaxf(o.x, 0.0f);
                o.y = fmaxf(o.y, 0.0f);
                o.z = fmaxf(o.z, 0.0f);
                o.w = fmaxf(o.w, 0.0f);
            }
            *(float4*)&out[(size_t)row * BN + col] = o;
        }
    }
}

// ---------------------------------------------------------------------------
// Kernel 4: tuple tail — pos_skip passthrough + batch_skip values.
// tailElems selects float32 vs raw-int64 batch layout. Only launched when
// out_size actually reserves space past the feature matrix (OOB guard).
// ---------------------------------------------------------------------------
__global__ __launch_bounds__(256) void tail_kernel(
    const float* __restrict__ pos_skip, float* __restrict__ out, int tailElems)
{
    const int i  = blockIdx.x * blockDim.x + threadIdx.x;
    const int PS = NROWS * 3;                       // 196608
    float* o1 = out + (size_t)NROWS * CHID;
    if (i < PS) o1[i] = pos_skip[i];
    if (i < NROWS) {
        const int bval = i >> 12;                   // i / NDST
        if (tailElems == NROWS) {
            o1[PS + i] = (float)bval;               // batch as float32
        } else if (tailElems == 2 * NROWS) {
            ((long long*)(o1 + PS))[i] = (long long)bval;  // batch kept as int64
        }
    }
}

// ---------------------------------------------------------------------------
extern "C" void kernel_launch(void* const* d_in, const int* in_sizes, int n_in,
                              void* d_out, int out_size, void* d_ws, size_t ws_size,
                              hipStream_t stream)
{
    const float* x        = (const float*)d_in[0];
    const float* pos      = (const float*)d_in[1];
    // d_in[2] = batch (unused; structure is static)
    const float* x_skip   = (const float*)d_in[3];
    const float* pos_skip = (const float*)d_in[4];
    // d_in[5] = batch_skip (unused; values are row/NDST)
    const float* W1 = (const float*)d_in[6];
    const float* b1 = (const float*)d_in[7];
    const float* W2 = (const float*)d_in[8];
    const float* b2 = (const float*)d_in[9];
    float* out = (float*)d_out;

    // workspace layout
    int*   nidx = (int*)d_ws;                          // 65536*3 ints   (768 KB)
    float* nw   = (float*)d_ws + NROWS * 3;            // 65536*3 floats (768 KB)
    float* h    = (float*)d_ws + 2 * NROWS * 3;        // 65536*256 floats (64 MB)

    knn_kernel<<<BB * (NDST / 256), 256, 0, stream>>>(pos, pos_skip, nidx, nw);

    mlp_gemm_kernel<CIN + CSKIP, true, true>
        <<<NROWS / 64, 256, 0, stream>>>(x, x_skip, nidx, nw, W1, b1, h);

    mlp_gemm_kernel<CHID, false, false>
        <<<NROWS / 64, 256, 0, stream>>>(h, nullptr, nullptr, nullptr, W2, b2, out);

    // Tuple tail: only write past the feature matrix if out_size reserves it.
    const int tail = out_size - NROWS * CHID - NROWS * 3;
    if (tail >= 0) {
        tail_kernel<<<(NROWS * 3 + 255) / 256, 256, 0, stream>>>(pos_skip, out, tail);
    }
}

// Round 8
// 297.076 us; speedup vs baseline: 1.8807x; 1.8807x over previous
//
#include <hip/hip_runtime.h>
#include <math.h>

// Problem constants (match reference)
#define BB    16
#define NSRC  1024
#define NDST  4096
#define CIN   256
#define CSKIP 128
#define CHID  256
#define NROWS (BB * NDST)   // 65536 output rows
#define K1    (CIN + CSKIP) // 384
#define K2    CHID          // 256

typedef __attribute__((ext_vector_type(8))) short bf16x8;   // 8 bf16 (4 VGPRs)
typedef __attribute__((ext_vector_type(4))) float f32x4;    // MFMA accum

// round-to-nearest-even f32 -> bf16 (matches XLA convert for normal values)
__device__ inline unsigned short f2bf(float f) {
    union { float f; unsigned u; } v; v.f = f;
    unsigned r = v.u + 0x7FFFu + ((v.u >> 16) & 1u);
    return (unsigned short)(r >> 16);
}

// ---------------------------------------------------------------------------
// Kernel 1: 3-NN per dst point within its cloud (float4-packed LDS src cloud).
// ---------------------------------------------------------------------------
__global__ __launch_bounds__(256) void knn_kernel(
    const float* __restrict__ pos,       // [BB*NSRC, 3]
    const float* __restrict__ pos_skip,  // [BB*NDST, 3]
    int*   __restrict__ nidx,            // [BB*NDST, 3]
    float* __restrict__ nw)              // [BB*NDST, 3]
{
    __shared__ float4 sp[NSRC];          // 16 KB
    const int bpc = NDST / 256;          // 16 blocks per cloud
    const int b   = blockIdx.x / bpc;
    const int r0  = (blockIdx.x % bpc) * 256;
    const int tid = threadIdx.x;

    const float* ps = pos + (size_t)b * NSRC * 3;
    for (int i = tid; i < NSRC; i += 256)
        sp[i] = make_float4(ps[i * 3 + 0], ps[i * 3 + 1], ps[i * 3 + 2], 0.f);
    __syncthreads();

    const int dr = b * NDST + r0 + tid;
    const float qx = pos_skip[dr * 3 + 0];
    const float qy = pos_skip[dr * 3 + 1];
    const float qz = pos_skip[dr * 3 + 2];

    float b0 = 3.4e38f, b1 = 3.4e38f, b2 = 3.4e38f;
    int   i0 = 0, i1 = 0, i2 = 0;
#pragma unroll 4
    for (int j = 0; j < NSRC; ++j) {
        const float4 p = sp[j];
        const float dx = qx - p.x, dy = qy - p.y, dz = qz - p.z;
        const float d  = dx * dx + dy * dy + dz * dz;
        if (d < b2) {                    // strict < keeps earlier index on ties
            if (d < b0)      { b2 = b1; i2 = i1; b1 = b0; i1 = i0; b0 = d; i0 = j; }
            else if (d < b1) { b2 = b1; i2 = i1; b1 = d;  i1 = j; }
            else             { b2 = d;  i2 = j; }
        }
    }
    const float w0 = 1.0f / (b0 + 1e-16f);
    const float w1 = 1.0f / (b1 + 1e-16f);
    const float w2 = 1.0f / (b2 + 1e-16f);
    const float inv = 1.0f / (w0 + w1 + w2);

    nidx[dr * 3 + 0] = b * NSRC + i0;
    nidx[dr * 3 + 1] = b * NSRC + i1;
    nidx[dr * 3 + 2] = b * NSRC + i2;
    nw[dr * 3 + 0] = w0 * inv;
    nw[dr * 3 + 1] = w1 * inv;
    nw[dr * 3 + 2] = w2 * inv;
}

// ---------------------------------------------------------------------------
// Kernel 2: one-shot W transpose + bf16 cast: Wt[n][k] = bf16(W[k][n]).
// ---------------------------------------------------------------------------
__global__ __launch_bounds__(256) void wt_kernel(
    const float* __restrict__ W1, const float* __restrict__ W2,
    unsigned short* __restrict__ W1t, unsigned short* __restrict__ W2t)
{
    const int id = blockIdx.x * 256 + threadIdx.x;
    if (id < 256 * K1) {
        const int n = id / K1, k = id % K1;
        W1t[id] = f2bf(W1[(size_t)k * 256 + n]);
    }
    if (id < 256 * K2) {
        const int n = id / K2, k = id % K2;
        W2t[id] = f2bf(W2[(size_t)k * 256 + n]);
    }
}

// ---------------------------------------------------------------------------
// Kernel 3/4: bf16 MFMA GEMM. BM=BN=128, BK=32, 256 threads (4 waves, 2x2).
// Each wave: 4x4 fragments of 16x16 (64x64 output), fp32 accum.
// FIRST: A = knn-interp(x) ++ x_skip (built on the fly, fp32->bf16);
//        epilogue relu -> h (bf16).
// !FIRST: A = h (bf16); epilogue -> out (fp32).
// LDS tiles padded [.][40] : row stride 80B -> 16B-aligned b128, 2-way banks.
// ---------------------------------------------------------------------------
template <int KDIM, bool FIRST>
__global__ __launch_bounds__(256) void mfma_gemm_kernel(
    const float* __restrict__ x,             // FIRST
    const float* __restrict__ x_skip,        // FIRST
    const unsigned short* __restrict__ hin,  // !FIRST
    const int*   __restrict__ nidx,          // FIRST
    const float* __restrict__ nw,            // FIRST
    const unsigned short* __restrict__ Wt,   // [256][KDIM] bf16 (B^T)
    const float* __restrict__ bias,          // [256]
    unsigned short* __restrict__ hout,       // FIRST
    float* __restrict__ fout)                // !FIRST
{
    constexpr int BM = 128, BN = 128, BK = 32, PAD = 40;
    __shared__ __align__(16) unsigned short At[BM][PAD];
    __shared__ __align__(16) unsigned short Bt[BN][PAD];
    __shared__ int   sIdx[BM][3];
    __shared__ float sW[BM][3];

    const int tid  = threadIdx.x;
    const int mblk = blockIdx.x >> 1;
    const int nblk = blockIdx.x & 1;
    const int rowBase = mblk * BM;
    const int nbase   = nblk * BN;

    if (FIRST && tid < BM) {
        const size_t g = (size_t)(rowBase + tid) * 3;
        sIdx[tid][0] = nidx[g + 0];
        sIdx[tid][1] = nidx[g + 1];
        sIdx[tid][2] = nidx[g + 2];
        sW[tid][0] = nw[g + 0];
        sW[tid][1] = nw[g + 1];
        sW[tid][2] = nw[g + 2];
    }
    __syncthreads();                       // sIdx/sW visible before staging

    f32x4 acc[4][4];
#pragma unroll
    for (int i = 0; i < 4; ++i)
#pragma unroll
        for (int j = 0; j < 4; ++j) acc[i][j] = (f32x4){0.f, 0.f, 0.f, 0.f};

    const int l  = tid & 63;
    const int w  = tid >> 6;
    const int wm = w >> 1, wn = w & 1;     // 2x2 wave grid
    const int cl = l & 15;                 // row/col within fragment
    const int k0 = (l >> 4) * 8;           // k-offset within fragment

    const int r  = tid >> 1;               // staging row (A and B tiles)
    const int kh = (tid & 1) * 16;         // staging k-offset

    for (int kt = 0; kt < KDIM; kt += BK) {
        // ---- stage A (16 bf16 per thread) into regs ----
        unsigned short a_s[16];
        if (FIRST) {
            const int c = kt + kh;
            if (kt < CIN) {                // interp gather: 3 x-rows, weighted
                const float4* x4 = (const float4*)x;
                const float w0 = sW[r][0], w1 = sW[r][1], w2 = sW[r][2];
                const size_t g0 = (size_t)sIdx[r][0] * (CIN / 4) + (c >> 2);
                const size_t g1 = (size_t)sIdx[r][1] * (CIN / 4) + (c >> 2);
                const size_t g2 = (size_t)sIdx[r][2] * (CIN / 4) + (c >> 2);
#pragma unroll
                for (int cc = 0; cc < 4; ++cc) {
                    const float4 f0 = x4[g0 + cc];
                    const float4 f1 = x4[g1 + cc];
                    const float4 f2 = x4[g2 + cc];
                    a_s[cc * 4 + 0] = f2bf(w0 * f0.x + w1 * f1.x + w2 * f2.x);
                    a_s[cc * 4 + 1] = f2bf(w0 * f0.y + w1 * f1.y + w2 * f2.y);
                    a_s[cc * 4 + 2] = f2bf(w0 * f0.z + w1 * f1.z + w2 * f2.z);
                    a_s[cc * 4 + 3] = f2bf(w0 * f0.w + w1 * f1.w + w2 * f2.w);
                }
            } else {                       // x_skip passthrough
                const float4* xs4 = (const float4*)x_skip;
                const size_t gs = (size_t)(rowBase + r) * (CSKIP / 4) + ((c - CIN) >> 2);
#pragma unroll
                for (int cc = 0; cc < 4; ++cc) {
                    const float4 f = xs4[gs + cc];
                    a_s[cc * 4 + 0] = f2bf(f.x);
                    a_s[cc * 4 + 1] = f2bf(f.y);
                    a_s[cc * 4 + 2] = f2bf(f.z);
                    a_s[cc * 4 + 3] = f2bf(f.w);
                }
            }
        } else {                           // A = h (already bf16)
            const unsigned short* hp = &hin[(size_t)(rowBase + r) * K2 + kt + kh];
            *(bf16x8*)&a_s[0] = *(const bf16x8*)&hp[0];
            *(bf16x8*)&a_s[8] = *(const bf16x8*)&hp[8];
        }
        // ---- stage B (16 bf16 per thread) into regs ----
        const unsigned short* wp = &Wt[(size_t)(nbase + r) * KDIM + kt + kh];
        const bf16x8 b_s0 = *(const bf16x8*)&wp[0];
        const bf16x8 b_s1 = *(const bf16x8*)&wp[8];

        __syncthreads();                   // prev step's MFMA reads done
        *(bf16x8*)&At[r][kh]     = *(bf16x8*)&a_s[0];
        *(bf16x8*)&At[r][kh + 8] = *(bf16x8*)&a_s[8];
        *(bf16x8*)&Bt[r][kh]     = b_s0;
        *(bf16x8*)&Bt[r][kh + 8] = b_s1;
        __syncthreads();                   // tile ready

        // ---- MFMA: 8 ds_read_b128 + 16 mfma per wave ----
        bf16x8 af[4], bf[4];
#pragma unroll
        for (int mt = 0; mt < 4; ++mt)
            af[mt] = *(const bf16x8*)&At[wm * 64 + mt * 16 + cl][k0];
#pragma unroll
        for (int nt = 0; nt < 4; ++nt)
            bf[nt] = *(const bf16x8*)&Bt[wn * 64 + nt * 16 + cl][k0];
#pragma unroll
        for (int mt = 0; mt < 4; ++mt)
#pragma unroll
            for (int nt = 0; nt < 4; ++nt)
                acc[mt][nt] = __builtin_amdgcn_mfma_f32_16x16x32_bf16(
                    af[mt], bf[nt], acc[mt][nt], 0, 0, 0);
    }

    // ---- epilogue: D layout col = l&15, row = (l>>4)*4 + reg [m89] ----
    const int rg = (l >> 4) * 4;
#pragma unroll
    for (int nt = 0; nt < 4; ++nt) {
        const int col = nbase + wn * 64 + nt * 16 + cl;
        const float bv = bias[col];
#pragma unroll
        for (int mt = 0; mt < 4; ++mt) {
            const int row = rowBase + wm * 64 + mt * 16 + rg;
#pragma unroll
            for (int rr = 0; rr < 4; ++rr) {
                float v = acc[mt][nt][rr] + bv;
                if (FIRST) {
                    v = fmaxf(v, 0.f);
                    hout[(size_t)(row + rr) * CHID + col] = f2bf(v);
                } else {
                    fout[(size_t)(row + rr) * CHID + col] = v;
                }
            }
        }
    }
}

// ---------------------------------------------------------------------------
// Kernel 5: tuple tail (guarded by out_size).
// ---------------------------------------------------------------------------
__global__ __launch_bounds__(256) void tail_kernel(
    const float* __restrict__ pos_skip, float* __restrict__ out, int tailElems)
{
    const int i  = blockIdx.x * blockDim.x + threadIdx.x;
    const int PS = NROWS * 3;
    float* o1 = out + (size_t)NROWS * CHID;
    if (i < PS) o1[i] = pos_skip[i];
    if (i < NROWS) {
        const int bval = i >> 12;          // i / NDST
        if (tailElems == NROWS) {
            o1[PS + i] = (float)bval;
        } else if (tailElems == 2 * NROWS) {
            ((long long*)(o1 + PS))[i] = (long long)bval;
        }
    }
}

// ---------------------------------------------------------------------------
extern "C" void kernel_launch(void* const* d_in, const int* in_sizes, int n_in,
                              void* d_out, int out_size, void* d_ws, size_t ws_size,
                              hipStream_t stream)
{
    const float* x        = (const float*)d_in[0];
    const float* pos      = (const float*)d_in[1];
    const float* x_skip   = (const float*)d_in[3];
    const float* pos_skip = (const float*)d_in[4];
    const float* W1 = (const float*)d_in[6];
    const float* b1 = (const float*)d_in[7];
    const float* W2 = (const float*)d_in[8];
    const float* b2 = (const float*)d_in[9];
    float* out = (float*)d_out;

    // workspace layout (fits prior-validated >=65.6 MB budget)
    int*   nidx = (int*)d_ws;                                   // 768 KB
    float* nw   = (float*)d_ws + NROWS * 3;                     // 768 KB
    unsigned short* h   = (unsigned short*)((float*)d_ws + 2 * NROWS * 3); // 32 MB bf16
    unsigned short* W1t = h + (size_t)NROWS * CHID;             // 192 KB
    unsigned short* W2t = W1t + 256 * K1;                       // 128 KB

    knn_kernel<<<BB * (NDST / 256), 256, 0, stream>>>(pos, pos_skip, nidx, nw);
    wt_kernel<<<(256 * K1 + 255) / 256, 256, 0, stream>>>(W1, W2, W1t, W2t);

    mfma_gemm_kernel<K1, true><<<(NROWS / 128) * 2, 256, 0, stream>>>(
        x, x_skip, nullptr, nidx, nw, W1t, b1, h, nullptr);

    mfma_gemm_kernel<K2, false><<<(NROWS / 128) * 2, 256, 0, stream>>>(
        nullptr, nullptr, h, nullptr, nullptr, W2t, b2, nullptr, out);

    const int tail = out_size - NROWS * CHID - NROWS * 3;
    if (tail >= 0) {
        tail_kernel<<<(NROWS * 3 + 255) / 256, 256, 0, stream>>>(pos_skip, out, tail);
    }
}